// Round 22
// baseline (229.744 us; speedup 1.0000x reference)
//
#include <hip/hip_runtime.h>
#include <math.h>

#define BB 8
#define NN 8192
#define CC 64
#define FE 32
#define KN 16
#define CP3 67
#define QPW 4                 // queries per wave (one per cell-rank stratum)
#define WPB 4                 // waves per block
#define CAPQ 64               // per-query stack (count-checked => exact)
#define YB 32
#define ZB 32
#define NCELL (YB * ZB)

// Device-global scratch (module .bss). All bytes written every launch before read.
__device__ double g_part[BB * CC * 2];        // per-(b,c) BN partial sums
__device__ float g_feat0[BB * NN * FE];       // 8 MB
__device__ int   g_idx[BB * NN * KN];         // 4 MB
__device__ float4 g_sorted[BB * NN];          // cell-sorted {x,y,z,xx}
__device__ int    g_sorig[BB * NN];           // sorted -> original index
__device__ unsigned g_binoff[BB * (NCELL + 1)];

// Identical in k_zbin and k_knn (same source => same bits; monotone).
__device__ __forceinline__ int cbin(float v) {
    int bi = (int)((v + 4.5f) * (32.0f / 9.0f));   // 32 bins over [-4.5,4.5]
    if (bi < 0) bi = 0;
    if (bi > 31) bi = 31;
    return bi;
}
// FROZEN reference xx (verified R5, XLA-CPU FMA contraction)
__device__ __forceinline__ float frz_xx(float x, float y, float z) {
    return __fmaf_rn(z, z, __fmaf_rn(y, y, __fmul_rn(x, x)));
}

// ---------------- kernel 1: BN partial sums, one block per (b,c) ----------
__global__ __launch_bounds__(256) void k_bnstats(const float* __restrict__ feat) {
    int bc = blockIdx.x;                        // b*64 + c, 512 blocks
    const float* p = feat + (size_t)bc * NN;    // coalesced single stream
    int tid = threadIdx.x;
    double s = 0.0, s2 = 0.0;
    for (int n = tid; n < NN; n += 256) {
        double v = (double)p[n];
        s += v; s2 += v * v;
    }
    __shared__ double sh[256], sh2[256];
    sh[tid] = s; sh2[tid] = s2;
    __syncthreads();
    for (int off = 128; off > 0; off >>= 1) {
        if (tid < off) { sh[tid] += sh[tid + off]; sh2[tid] += sh2[tid + off]; }
        __syncthreads();
    }
    if (tid == 0) {
        g_part[bc * 2]     = sh[0];
        g_part[bc * 2 + 1] = sh2[0];
    }
}

// ---------------- kernel 1b: (y,z) cell binning -----------------------
__global__ __launch_bounds__(1024) void k_zbin(const float* __restrict__ xyz) {
    __shared__ unsigned hist[NCELL];
    __shared__ unsigned scan[NCELL];
    __shared__ unsigned boff[NCELL + 1];
    int b = blockIdx.x;
    int tid = threadIdx.x;
    hist[tid] = 0;
    __syncthreads();
    const float* bx = xyz + (size_t)b * NN * 3;
    for (int n = tid; n < NN; n += 1024) {
        float y = bx[n * 3 + 1], z = bx[n * 3 + 2];
        atomicAdd(&hist[cbin(y) * ZB + cbin(z)], 1u);
    }
    __syncthreads();
    scan[tid] = hist[tid];
    __syncthreads();
    for (int off = 1; off < NCELL; off <<= 1) {
        unsigned add = (tid >= off) ? scan[tid - off] : 0u;
        __syncthreads();
        scan[tid] += add;
        __syncthreads();
    }
    if (tid == 0) boff[0] = 0;
    boff[tid + 1] = scan[tid];
    __syncthreads();
    hist[tid] = 0;                               // reuse as cursors
    g_binoff[b * (NCELL + 1) + tid + 1] = boff[tid + 1];
    if (tid == 0) g_binoff[b * (NCELL + 1)] = 0;
    __syncthreads();
    for (int n = tid; n < NN; n += 1024) {
        const float* p = bx + (size_t)n * 3;
        float x = p[0], y = p[1], z = p[2];
        int cell = cbin(y) * ZB + cbin(z);
        unsigned pos = boff[cell] + atomicAdd(&hist[cell], 1u);
        g_sorted[(size_t)b * NN + pos] = make_float4(x, y, z, frz_xx(x, y, z));
        g_sorig[(size_t)b * NN + pos] = n;
    }
}

// ---------------- kernel 2: feat0 = Wg' * [feat;xyz] + bias0 ----------------
__global__ __launch_bounds__(256) void k_feat0(const float* __restrict__ feat,
        const float* __restrict__ xyz, const float* __restrict__ Wg,
        const float* __restrict__ gamma, const float* __restrict__ beta) {
    __shared__ float scs[CC], shs[CC];
    __shared__ float wgs[CP3 * FE];
    __shared__ float bias0[FE];
    int tid = threadIdx.x;
    if (tid < CC) {
        double s = 0.0, s2 = 0.0;
        for (int bb2 = 0; bb2 < BB; ++bb2) {
            s  += g_part[((bb2 << 6) + tid) * 2];
            s2 += g_part[((bb2 << 6) + tid) * 2 + 1];
        }
        double inv = 1.0 / (double)(BB * NN);
        double mean = s * inv;
        double var = s2 * inv - mean * mean;
        float sc = gamma[tid] * (float)(1.0 / sqrt(var + (double)1e-5f));
        scs[tid] = sc;
        shs[tid] = beta[tid] - sc * (float)mean;
    }
    __syncthreads();
    for (int i = tid; i < CP3 * FE; i += 256) {
        int c = i >> 5, e = i & 31;
        float w = Wg[e * CP3 + c];
        if (c < CC) w *= scs[c];
        wgs[c * FE + e] = w;
    }
    if (tid < FE) {
        float sacc = 0.f;
        for (int c = 0; c < CC; ++c) sacc = fmaf(Wg[tid * CP3 + c], shs[c], sacc);
        bias0[tid] = sacc;
    }
    __syncthreads();
    int b = blockIdx.x >> 5;
    int n = ((blockIdx.x & 31) << 8) + tid;
    const float* pz = xyz + ((size_t)(b * NN + n)) * 3;
    float x = pz[0], y = pz[1], z = pz[2];

    float acc[FE];
    #pragma unroll
    for (int e = 0; e < FE; ++e) acc[e] = bias0[e];
    const float* fp = feat + (size_t)b * CC * NN + n;
    for (int c = 0; c < CC; ++c) {
        float v = fp[(size_t)c * NN];
        const float4* w4 = (const float4*)(wgs + c * FE);
        #pragma unroll
        for (int e0 = 0; e0 < 8; ++e0) {
            float4 w = w4[e0];
            acc[e0 * 4 + 0] = fmaf(w.x, v, acc[e0 * 4 + 0]);
            acc[e0 * 4 + 1] = fmaf(w.y, v, acc[e0 * 4 + 1]);
            acc[e0 * 4 + 2] = fmaf(w.z, v, acc[e0 * 4 + 2]);
            acc[e0 * 4 + 3] = fmaf(w.w, v, acc[e0 * 4 + 3]);
        }
    }
    #pragma unroll
    for (int d = 0; d < 3; ++d) {
        float v = (d == 0) ? x : ((d == 1) ? y : z);
        const float4* w4 = (const float4*)(wgs + (CC + d) * FE);
        #pragma unroll
        for (int e0 = 0; e0 < 8; ++e0) {
            float4 w = w4[e0];
            acc[e0 * 4 + 0] = fmaf(w.x, v, acc[e0 * 4 + 0]);
            acc[e0 * 4 + 1] = fmaf(w.y, v, acc[e0 * 4 + 1]);
            acc[e0 * 4 + 2] = fmaf(w.z, v, acc[e0 * 4 + 2]);
            acc[e0 * 4 + 3] = fmaf(w.w, v, acc[e0 * 4 + 3]);
        }
    }
    float4* outp = (float4*)(g_feat0 + ((size_t)(b * NN + n)) * FE);
    #pragma unroll
    for (int e0 = 0; e0 < 8; ++e0)
        outp[e0] = make_float4(acc[e0 * 4 + 0], acc[e0 * 4 + 1], acc[e0 * 4 + 2], acc[e0 * 4 + 3]);
}

// ---------------- kernel 3: two-stream cell-windowed stratified KNN -------
// FROZEN reference arithmetic (verified R5):
//   dot  = fma(zq,zm, fma(yq,ym, xq*xm))
//   dist = fadd( fma(-2, dot, xx_q), xx_m )
// R22 = R21 + TWO INTERLEAVED QUERY STREAMS per wave (strata pairs (i,i+1)):
// two independent cursors/windows advanced+prefetched in one loop -> 4 loads
// in flight, 2x VALU per stall window. R21 counters (VALUBusy 46%, occ 37%)
// showed the single dependent load chain as the cap. If one stream finishes
// (or retries while the other accepted) the loop degenerates to the proven
// single-stream path; all conditions wave-uniform. Per-stream machinery
// byte-identical: cell-window coverage (R18), gate+count-check [16,64],
// bracketed bisection (R12), counting-rank (R13), SO[] for passers (R15)
// => identical neighbor sets.
__global__ __launch_bounds__(256) void k_knn() {
    __shared__ unsigned long long qbuf[WPB * 2 * CAPQ];   // 4 KB
    int tid = threadIdx.x;
    int lane = tid & 63;
    int w = tid >> 6;
    int wid = blockIdx.x * WPB + w;             // 0..16383
    int b = wid >> 11;                          // 2048 waves per batch
    int g = wid & 2047;
    const float4* S = g_sorted + (size_t)b * NN;
    const int* SO = g_sorig + (size_t)b * NN;
    const unsigned* BO = g_binoff + b * (NCELL + 1);
    unsigned long long lt = (1ull << lane) - 1ull;
    unsigned long long* pbA = qbuf + (w * 2 + 0) * CAPQ;
    unsigned long long* pbB = qbuf + (w * 2 + 1) * CAPQ;

    #pragma unroll 1
    for (int pr2 = 0; pr2 < 2; ++pr2) {
        int qrA = g + ((pr2 * 2) << 11);        // stratum 2*pr2
        int qrB = g + ((pr2 * 2 + 1) << 11);    // stratum 2*pr2+1
        float4 qvA = S[qrA], qvB = S[qrB];
        int qoA = SO[qrA], qoB = SO[qrB];
        float t0A, t0B;
        { float t = 0.053f * __expf(qvA.w * (1.0f / 3.0f)); t0A = t > 3.f ? 3.f : t; }
        { float t = 0.053f * __expf(qvB.w * (1.0f / 3.0f)); t0B = t > 3.f ? 3.f : t; }
        float tloA = 0.f, thiA = 0.f, tloB = 0.f, thiB = 0.f;
        unsigned cntA = 0, cntB = 0;
        bool dnA = false, dnB = false;

        for (int attempt = 0; attempt < 40; ++attempt) {
            if (dnA && dnB) break;
            // ---- window + cursor init per active stream ----
            int ybA = 0, pA = 0, hiA = 0, yhiA = 0, zloA = 0, zhiA = 0;
            bool haveA = false; int jcA = 0; bool incA = false;
            float4 curA = make_float4(0.f, 0.f, 0.f, 1e30f);
            if (!dnA) {
                cntA = 0;
                float R = __fsqrt_rn(t0A + 1e-3f) + 1e-3f;
                int ylo = cbin(qvA.y - R); yhiA = cbin(qvA.y + R);
                zloA = cbin(qvA.z - R); zhiA = cbin(qvA.z + R);
                ybA = ylo;
                pA = (int)BO[ybA * ZB + zloA];
                hiA = (int)BO[ybA * ZB + zhiA + 1];
                while (pA >= hiA && ybA < yhiA) {
                    ++ybA;
                    pA = (int)BO[ybA * ZB + zloA];
                    hiA = (int)BO[ybA * ZB + zhiA + 1];
                }
                haveA = pA < hiA;
                if (haveA) {
                    jcA = pA + lane; if (jcA > hiA - 1) jcA = hiA - 1;
                    curA = S[jcA];
                    incA = (pA + lane) < hiA;
                }
            }
            int ybB = 0, pB = 0, hiB = 0, yhiB = 0, zloB = 0, zhiB = 0;
            bool haveB = false; int jcB = 0; bool incB = false;
            float4 curB = make_float4(0.f, 0.f, 0.f, 1e30f);
            if (!dnB) {
                cntB = 0;
                float R = __fsqrt_rn(t0B + 1e-3f) + 1e-3f;
                int ylo = cbin(qvB.y - R); yhiB = cbin(qvB.y + R);
                zloB = cbin(qvB.z - R); zhiB = cbin(qvB.z + R);
                ybB = ylo;
                pB = (int)BO[ybB * ZB + zloB];
                hiB = (int)BO[ybB * ZB + zhiB + 1];
                while (pB >= hiB && ybB < yhiB) {
                    ++ybB;
                    pB = (int)BO[ybB * ZB + zloB];
                    hiB = (int)BO[ybB * ZB + zhiB + 1];
                }
                haveB = pB < hiB;
                if (haveB) {
                    jcB = pB + lane; if (jcB > hiB - 1) jcB = hiB - 1;
                    curB = S[jcB];
                    incB = (pB + lane) < hiB;
                }
            }
            // ---- interleaved scan ----
            while (haveA || haveB) {
                // advance + prefetch A
                int ybA2 = ybA, pA2 = pA + 64, hiA2 = hiA; bool haveA2 = false;
                int jnA = jcA; float4 nxtA = curA; bool innA = false;
                if (haveA) {
                    while (pA2 >= hiA2 && ybA2 < yhiA) {
                        ++ybA2;
                        pA2 = (int)BO[ybA2 * ZB + zloA];
                        hiA2 = (int)BO[ybA2 * ZB + zhiA + 1];
                    }
                    haveA2 = pA2 < hiA2;
                    if (haveA2) {
                        jnA = pA2 + lane; if (jnA > hiA2 - 1) jnA = hiA2 - 1;
                        nxtA = S[jnA];
                        innA = (pA2 + lane) < hiA2;
                    }
                }
                // advance + prefetch B
                int ybB2 = ybB, pB2 = pB + 64, hiB2 = hiB; bool haveB2 = false;
                int jnB = jcB; float4 nxtB = curB; bool innB = false;
                if (haveB) {
                    while (pB2 >= hiB2 && ybB2 < yhiB) {
                        ++ybB2;
                        pB2 = (int)BO[ybB2 * ZB + zloB];
                        hiB2 = (int)BO[ybB2 * ZB + zhiB + 1];
                    }
                    haveB2 = pB2 < hiB2;
                    if (haveB2) {
                        jnB = pB2 + lane; if (jnB > hiB2 - 1) jnB = hiB2 - 1;
                        nxtB = S[jnB];
                        innB = (pB2 + lane) < hiB2;
                    }
                }
                // process current A
                if (haveA) {
                    float dot = __fmaf_rn(qvA.z, curA.z, __fmaf_rn(qvA.y, curA.y, __fmul_rn(qvA.x, curA.x)));
                    float dist = __fadd_rn(__fmaf_rn(-2.f, dot, qvA.w), curA.w);
                    bool pr = (dist <= t0A) && incA;
                    unsigned long long mask = __ballot(pr);
                    if (mask) {
                        unsigned pos = cntA + (unsigned)__popcll(mask & lt);
                        if (pr && pos < CAPQ) {
                            int corig = SO[jcA];
                            int db = __float_as_int(dist);
                            unsigned key = (unsigned)db ^ (unsigned)((db >> 31) | 0x80000000);
                            pbA[pos] = ((unsigned long long)key << 32) | (unsigned)corig;
                        }
                        cntA += (unsigned)__popcll(mask);
                    }
                }
                // process current B
                if (haveB) {
                    float dot = __fmaf_rn(qvB.z, curB.z, __fmaf_rn(qvB.y, curB.y, __fmul_rn(qvB.x, curB.x)));
                    float dist = __fadd_rn(__fmaf_rn(-2.f, dot, qvB.w), curB.w);
                    bool pr = (dist <= t0B) && incB;
                    unsigned long long mask = __ballot(pr);
                    if (mask) {
                        unsigned pos = cntB + (unsigned)__popcll(mask & lt);
                        if (pr && pos < CAPQ) {
                            int corig = SO[jcB];
                            int db = __float_as_int(dist);
                            unsigned key = (unsigned)db ^ (unsigned)((db >> 31) | 0x80000000);
                            pbB[pos] = ((unsigned long long)key << 32) | (unsigned)corig;
                        }
                        cntB += (unsigned)__popcll(mask);
                    }
                }
                // rotate
                ybA = ybA2; pA = pA2; hiA = hiA2; haveA = haveA2;
                jcA = jnA; curA = nxtA; incA = innA;
                ybB = ybB2; pB = pB2; hiB = hiB2; haveB = haveB2;
                jcB = jnB; curB = nxtB; incB = innB;
            }
            // ---- accept / retry decisions (independent, proven R12 logic) ----
            if (!dnA) {
                if (cntA < KN) {
                    tloA = t0A;
                    t0A = (thiA > 0.f) ? __fsqrt_rn(tloA * thiA) : t0A * 2.0f;
                } else if (cntA > CAPQ) {
                    thiA = t0A;
                    t0A = (tloA > 0.f) ? __fsqrt_rn(tloA * thiA) : t0A * 0.5f;
                } else dnA = true;
            }
            if (!dnB) {
                if (cntB < KN) {
                    tloB = t0B;
                    t0B = (thiB > 0.f) ? __fsqrt_rn(tloB * thiB) : t0B * 2.0f;
                } else if (cntB > CAPQ) {
                    thiB = t0B;
                    t0B = (tloB > 0.f) ? __fsqrt_rn(tloB * thiB) : t0B * 0.5f;
                } else dnB = true;
            }
        }

        // ---- selection: counting-rank per stream (CAPQ=64 -> 1/lane) ----
        {
            unsigned tot = cntA > CAPQ ? CAPQ : cntA;
            unsigned long long e0 = ((unsigned)lane < tot) ? pbA[lane] : ~0ull;
            unsigned rank0 = 0;
            for (unsigned jx = 0; jx < tot; ++jx)
                rank0 += (pbA[jx] < e0) ? 1u : 0u;
            if (((unsigned)lane < tot) && rank0 < KN)
                g_idx[(b * NN + qoA) * KN + rank0] = (int)(e0 & 0xffffffffull);
        }
        {
            unsigned tot = cntB > CAPQ ? CAPQ : cntB;
            unsigned long long e0 = ((unsigned)lane < tot) ? pbB[lane] : ~0ull;
            unsigned rank0 = 0;
            for (unsigned jx = 0; jx < tot; ++jx)
                rank0 += (pbB[jx] < e0) ? 1u : 0u;
            if (((unsigned)lane < tot) && rank0 < KN)
                g_idx[(b * NN + qoB) * KN + rank0] = (int)(e0 & 0xffffffffull);
        }
    }
}

// ---------------- kernel 4: gather+max, rel, out = Wh' * rel ----------------
__global__ __launch_bounds__(256) void k_out(const float* __restrict__ Wh,
        float* __restrict__ out) {
    __shared__ float whs[CC * FE];
    int tid = threadIdx.x;
    for (int i = tid; i < CC * FE; i += 256) {
        int c = i >> 5, e = i & 31;
        float s = 0.f;
        #pragma unroll
        for (int m = 0; m < 4; ++m) s += Wh[c * 128 + m * 32 + e];
        whs[i] = s;
    }
    __syncthreads();
    int b = blockIdx.x >> 5;
    int n = ((blockIdx.x & 31) << 8) + tid;
    const int* ip = g_idx + (size_t)(b * NN + n) * KN;
    const float4* f0 = (const float4*)(g_feat0 + (size_t)b * NN * FE);
    float gmax[FE];
    #pragma unroll
    for (int e = 0; e < FE; ++e) gmax[e] = -__builtin_inff();
    for (int k = 0; k < KN; ++k) {
        int id = ip[k] & (NN - 1);      // defensive mask, no-op for valid idx
        const float4* row = f0 + (size_t)id * 8;
        #pragma unroll
        for (int e0 = 0; e0 < 8; ++e0) {
            float4 v = row[e0];
            gmax[e0 * 4 + 0] = fmaxf(gmax[e0 * 4 + 0], v.x);
            gmax[e0 * 4 + 1] = fmaxf(gmax[e0 * 4 + 1], v.y);
            gmax[e0 * 4 + 2] = fmaxf(gmax[e0 * 4 + 2], v.z);
            gmax[e0 * 4 + 3] = fmaxf(gmax[e0 * 4 + 3], v.w);
        }
    }
    const float4* selfr = f0 + (size_t)n * 8;
    float rel[FE];
    #pragma unroll
    for (int e0 = 0; e0 < 8; ++e0) {
        float4 v = selfr[e0];
        rel[e0 * 4 + 0] = gmax[e0 * 4 + 0] - v.x;
        rel[e0 * 4 + 1] = gmax[e0 * 4 + 1] - v.y;
        rel[e0 * 4 + 2] = gmax[e0 * 4 + 2] - v.z;
        rel[e0 * 4 + 3] = gmax[e0 * 4 + 3] - v.w;
    }
    float* op = out + (size_t)b * CC * NN + n;
    for (int c = 0; c < CC; ++c) {
        const float4* w4 = (const float4*)(whs + c * FE);
        float s = 0.f;
        #pragma unroll
        for (int e0 = 0; e0 < 8; ++e0) {
            float4 w = w4[e0];
            s = fmaf(w.x, rel[e0 * 4 + 0], s);
            s = fmaf(w.y, rel[e0 * 4 + 1], s);
            s = fmaf(w.z, rel[e0 * 4 + 2], s);
            s = fmaf(w.w, rel[e0 * 4 + 3], s);
        }
        op[(size_t)c * NN] = s;
    }
}

extern "C" void kernel_launch(void* const* d_in, const int* in_sizes, int n_in,
                              void* d_out, int out_size, void* d_ws, size_t ws_size,
                              hipStream_t stream) {
    const float* xyz   = (const float*)d_in[0];
    const float* feat  = (const float*)d_in[1];
    const float* gamma = (const float*)d_in[2];
    const float* beta  = (const float*)d_in[3];
    const float* Wg    = (const float*)d_in[4];
    const float* Wh    = (const float*)d_in[5];
    float* out = (float*)d_out;
    (void)d_ws; (void)ws_size;

    hipLaunchKernelGGL(k_bnstats, dim3(512),  dim3(256),  0, stream, feat);
    hipLaunchKernelGGL(k_zbin,    dim3(8),    dim3(1024), 0, stream, xyz);
    hipLaunchKernelGGL(k_feat0,   dim3(256),  dim3(256),  0, stream, feat, xyz, Wg, gamma, beta);
    hipLaunchKernelGGL(k_knn,     dim3(4096), dim3(256),  0, stream);
    hipLaunchKernelGGL(k_out,     dim3(256),  dim3(256),  0, stream, Wh, out);
}

// Round 23
// 200.667 us; speedup vs baseline: 1.1449x; 1.1449x over previous
//
#include <hip/hip_runtime.h>
#include <math.h>

#define BB 8
#define NN 8192
#define CC 64
#define FE 32
#define KN 16
#define CP3 67
#define QPW 4                 // queries per wave (one per cell-rank stratum)
#define WPB 4                 // waves per block
#define CAPQ 64               // per-query stack (count-checked => exact)
#define YB 32
#define ZB 32
#define NCELL (YB * ZB)

// Device-global scratch (module .bss). All bytes written every launch before read.
__device__ double g_part[BB * CC * 2];        // per-(b,c) BN partial sums
__device__ float g_feat0[BB * NN * FE];       // 8 MB
__device__ int   g_idx[BB * NN * KN];         // 4 MB
__device__ float4 g_sorted[BB * NN];          // cell-sorted {x,y,z,xx}
__device__ int    g_sorig[BB * NN];           // sorted -> original index
__device__ unsigned g_binoff[BB * (NCELL + 1)];

// Identical in k_zbin and k_knn (same source => same bits; monotone).
__device__ __forceinline__ int cbin(float v) {
    int bi = (int)((v + 4.5f) * (32.0f / 9.0f));   // 32 bins over [-4.5,4.5]
    if (bi < 0) bi = 0;
    if (bi > 31) bi = 31;
    return bi;
}
// FROZEN reference xx (verified R5, XLA-CPU FMA contraction)
__device__ __forceinline__ float frz_xx(float x, float y, float z) {
    return __fmaf_rn(z, z, __fmaf_rn(y, y, __fmul_rn(x, x)));
}

// ---------------- kernel 1: BN partial sums, one block per (b,c) ----------
__global__ __launch_bounds__(256) void k_bnstats(const float* __restrict__ feat) {
    int bc = blockIdx.x;                        // b*64 + c, 512 blocks
    const float* p = feat + (size_t)bc * NN;    // coalesced single stream
    int tid = threadIdx.x;
    double s = 0.0, s2 = 0.0;
    for (int n = tid; n < NN; n += 256) {
        double v = (double)p[n];
        s += v; s2 += v * v;
    }
    __shared__ double sh[256], sh2[256];
    sh[tid] = s; sh2[tid] = s2;
    __syncthreads();
    for (int off = 128; off > 0; off >>= 1) {
        if (tid < off) { sh[tid] += sh[tid + off]; sh2[tid] += sh2[tid + off]; }
        __syncthreads();
    }
    if (tid == 0) {
        g_part[bc * 2]     = sh[0];
        g_part[bc * 2 + 1] = sh2[0];
    }
}

// ---------------- kernel 1b: (y,z) cell binning -----------------------
__global__ __launch_bounds__(1024) void k_zbin(const float* __restrict__ xyz) {
    __shared__ unsigned hist[NCELL];
    __shared__ unsigned scan[NCELL];
    __shared__ unsigned boff[NCELL + 1];
    int b = blockIdx.x;
    int tid = threadIdx.x;
    hist[tid] = 0;
    __syncthreads();
    const float* bx = xyz + (size_t)b * NN * 3;
    for (int n = tid; n < NN; n += 1024) {
        float y = bx[n * 3 + 1], z = bx[n * 3 + 2];
        atomicAdd(&hist[cbin(y) * ZB + cbin(z)], 1u);
    }
    __syncthreads();
    scan[tid] = hist[tid];
    __syncthreads();
    for (int off = 1; off < NCELL; off <<= 1) {
        unsigned add = (tid >= off) ? scan[tid - off] : 0u;
        __syncthreads();
        scan[tid] += add;
        __syncthreads();
    }
    if (tid == 0) boff[0] = 0;
    boff[tid + 1] = scan[tid];
    __syncthreads();
    hist[tid] = 0;                               // reuse as cursors
    g_binoff[b * (NCELL + 1) + tid + 1] = boff[tid + 1];
    if (tid == 0) g_binoff[b * (NCELL + 1)] = 0;
    __syncthreads();
    for (int n = tid; n < NN; n += 1024) {
        const float* p = bx + (size_t)n * 3;
        float x = p[0], y = p[1], z = p[2];
        int cell = cbin(y) * ZB + cbin(z);
        unsigned pos = boff[cell] + atomicAdd(&hist[cell], 1u);
        g_sorted[(size_t)b * NN + pos] = make_float4(x, y, z, frz_xx(x, y, z));
        g_sorig[(size_t)b * NN + pos] = n;
    }
}

// ---------------- kernel 2: feat0 = Wg' * [feat;xyz] + bias0 ----------------
__global__ __launch_bounds__(256) void k_feat0(const float* __restrict__ feat,
        const float* __restrict__ xyz, const float* __restrict__ Wg,
        const float* __restrict__ gamma, const float* __restrict__ beta) {
    __shared__ float scs[CC], shs[CC];
    __shared__ float wgs[CP3 * FE];
    __shared__ float bias0[FE];
    int tid = threadIdx.x;
    if (tid < CC) {
        double s = 0.0, s2 = 0.0;
        for (int bb2 = 0; bb2 < BB; ++bb2) {
            s  += g_part[((bb2 << 6) + tid) * 2];
            s2 += g_part[((bb2 << 6) + tid) * 2 + 1];
        }
        double inv = 1.0 / (double)(BB * NN);
        double mean = s * inv;
        double var = s2 * inv - mean * mean;
        float sc = gamma[tid] * (float)(1.0 / sqrt(var + (double)1e-5f));
        scs[tid] = sc;
        shs[tid] = beta[tid] - sc * (float)mean;
    }
    __syncthreads();
    for (int i = tid; i < CP3 * FE; i += 256) {
        int c = i >> 5, e = i & 31;
        float w = Wg[e * CP3 + c];
        if (c < CC) w *= scs[c];
        wgs[c * FE + e] = w;
    }
    if (tid < FE) {
        float sacc = 0.f;
        for (int c = 0; c < CC; ++c) sacc = fmaf(Wg[tid * CP3 + c], shs[c], sacc);
        bias0[tid] = sacc;
    }
    __syncthreads();
    int b = blockIdx.x >> 5;
    int n = ((blockIdx.x & 31) << 8) + tid;
    const float* pz = xyz + ((size_t)(b * NN + n)) * 3;
    float x = pz[0], y = pz[1], z = pz[2];

    float acc[FE];
    #pragma unroll
    for (int e = 0; e < FE; ++e) acc[e] = bias0[e];
    const float* fp = feat + (size_t)b * CC * NN + n;
    for (int c = 0; c < CC; ++c) {
        float v = fp[(size_t)c * NN];
        const float4* w4 = (const float4*)(wgs + c * FE);
        #pragma unroll
        for (int e0 = 0; e0 < 8; ++e0) {
            float4 w = w4[e0];
            acc[e0 * 4 + 0] = fmaf(w.x, v, acc[e0 * 4 + 0]);
            acc[e0 * 4 + 1] = fmaf(w.y, v, acc[e0 * 4 + 1]);
            acc[e0 * 4 + 2] = fmaf(w.z, v, acc[e0 * 4 + 2]);
            acc[e0 * 4 + 3] = fmaf(w.w, v, acc[e0 * 4 + 3]);
        }
    }
    #pragma unroll
    for (int d = 0; d < 3; ++d) {
        float v = (d == 0) ? x : ((d == 1) ? y : z);
        const float4* w4 = (const float4*)(wgs + (CC + d) * FE);
        #pragma unroll
        for (int e0 = 0; e0 < 8; ++e0) {
            float4 w = w4[e0];
            acc[e0 * 4 + 0] = fmaf(w.x, v, acc[e0 * 4 + 0]);
            acc[e0 * 4 + 1] = fmaf(w.y, v, acc[e0 * 4 + 1]);
            acc[e0 * 4 + 2] = fmaf(w.z, v, acc[e0 * 4 + 2]);
            acc[e0 * 4 + 3] = fmaf(w.w, v, acc[e0 * 4 + 3]);
        }
    }
    float4* outp = (float4*)(g_feat0 + ((size_t)(b * NN + n)) * FE);
    #pragma unroll
    for (int e0 = 0; e0 < 8; ++e0)
        outp[e0] = make_float4(acc[e0 * 4 + 0], acc[e0 * 4 + 1], acc[e0 * 4 + 2], acc[e0 * 4 + 3]);
}

// ---------------- kernel 3: circle-trimmed 128-chunk stratified KNN -------
// FROZEN reference arithmetic (verified R5):
//   dot  = fma(zq,zm, fma(yq,ym, xq*xm))
//   dist = fadd( fma(-2, dot, xx_q), xx_m )
// R23 = R21 single-stream structure (R22's dual-stream regressed: max-of-
// windows loop + VGPR 36) with two in-chain changes:
//  (a) 128-cand chunks, 2 cands/lane (contiguous 32B/lane, 2 independent
//      loads/step): halves loop iterations, doubles MLP, no extra cursor
//      state. Push ORDER changes but counting-rank sorts by (dist,idx) key
//      and the count-check only needs the passer SET + exact cnt => same
//      neighbor sets.
//  (b) per-row circular z-trim: row yb scans z in [qz-Rz, qz+Rz], Rz =
//      sqrt(t0+1e-3 - dymin^2)+1e-3, dymin = dist(qy, row interval); row
//      bounds 0.28125*yb-4.5 exact binary. Passer coverage: (cy-qy)^2 <=
//      dist+5e-6 and dymin_true >= dymin-2e-7 => 1e-3 slacks dominate all
//      rounding (R18-style proof). Window still superset of gate set =>
//      cnt = |gate set|, monotone in t0 => R12 bisection proof unchanged.
__global__ __launch_bounds__(256) void k_knn() {
    __shared__ unsigned long long qbuf[WPB * CAPQ];   // 2 KB
    int tid = threadIdx.x;
    int lane = tid & 63;
    int w = tid >> 6;
    int wid = blockIdx.x * WPB + w;             // 0..16383
    int b = wid >> 11;                          // 2048 waves per batch
    int g = wid & 2047;
    const float4* S = g_sorted + (size_t)b * NN;
    const int* SO = g_sorig + (size_t)b * NN;
    const unsigned* BO = g_binoff + b * (NCELL + 1);
    unsigned long long lt = (1ull << lane) - 1ull;
    unsigned long long* pb = qbuf + w * CAPQ;

    #pragma unroll 1
    for (int i = 0; i < QPW; ++i) {
        int qrank = g + (i << 11);              // stratum i sample
        float4 qv = S[qrank];
        float qx = qv.x, qy = qv.y, qz = qv.z, qxx = qv.w;
        int qorig = SO[qrank];
        float tt = 0.053f * __expf(qxx * (1.0f / 3.0f));   // ~32 expected passers
        float t0 = tt > 3.f ? 3.f : tt;
        float tlo = 0.f, thi = 0.f;             // bracket ends (0 = unset)
        unsigned cnt = 0;

        for (int attempt = 0; attempt < 40; ++attempt) {
            cnt = 0;
            float tpe = t0 + 1e-3f;
            float R = __fsqrt_rn(tpe) + 1e-3f;
            int ylo = cbin(qy - R), yhi = cbin(qy + R);

            // enter first nonempty row segment (circle-trimmed z range)
            int yb = ylo, p = 0, hi = 0;
            {
                float rowlo = 0.28125f * (float)yb - 4.5f;
                float dy = fmaxf(0.f, fmaxf(rowlo - qy, qy - (rowlo + 0.28125f)));
                float rz2 = tpe - dy * dy;
                if (rz2 > 0.f) {
                    float Rz = __fsqrt_rn(rz2) + 1e-3f;
                    int zl = cbin(qz - Rz), zh = cbin(qz + Rz);
                    p = (int)BO[yb * ZB + zl]; hi = (int)BO[yb * ZB + zh + 1];
                }
            }
            while (p >= hi && yb < yhi) {
                ++yb;
                float rowlo = 0.28125f * (float)yb - 4.5f;
                float dy = fmaxf(0.f, fmaxf(rowlo - qy, qy - (rowlo + 0.28125f)));
                float rz2 = tpe - dy * dy;
                if (rz2 > 0.f) {
                    float Rz = __fsqrt_rn(rz2) + 1e-3f;
                    int zl = cbin(qz - Rz), zh = cbin(qz + Rz);
                    p = (int)BO[yb * ZB + zl]; hi = (int)BO[yb * ZB + zh + 1];
                } else { p = 0; hi = 0; }
            }
            bool have = p < hi;
            int jc0 = 0, jc1 = 0; bool in0 = false, in1 = false;
            float4 c0, c1;
            if (have) {
                int base = p + 2 * lane;
                jc0 = base < hi ? base : hi - 1;
                jc1 = base + 1 < hi ? base + 1 : hi - 1;
                c0 = S[jc0]; c1 = S[jc1];
                in0 = base < hi; in1 = base + 1 < hi;
            }
            while (have) {
                // advance cursor (uniform) + prefetch next 128-chunk
                int yb2 = yb, p2 = p + 128, hi2 = hi;
                while (p2 >= hi2 && yb2 < yhi) {
                    ++yb2;
                    float rowlo = 0.28125f * (float)yb2 - 4.5f;
                    float dy = fmaxf(0.f, fmaxf(rowlo - qy, qy - (rowlo + 0.28125f)));
                    float rz2 = tpe - dy * dy;
                    if (rz2 > 0.f) {
                        float Rz = __fsqrt_rn(rz2) + 1e-3f;
                        int zl = cbin(qz - Rz), zh = cbin(qz + Rz);
                        p2 = (int)BO[yb2 * ZB + zl]; hi2 = (int)BO[yb2 * ZB + zh + 1];
                    } else { p2 = 0; hi2 = 0; }
                }
                bool have2 = p2 < hi2;
                int jn0 = jc0, jn1 = jc1; bool inn0 = false, inn1 = false;
                float4 n0 = c0, n1 = c1;
                if (have2) {
                    int base = p2 + 2 * lane;
                    jn0 = base < hi2 ? base : hi2 - 1;
                    jn1 = base + 1 < hi2 ? base + 1 : hi2 - 1;
                    n0 = S[jn0]; n1 = S[jn1];
                    inn0 = base < hi2; inn1 = base + 1 < hi2;
                }
                // process current chunk (2 cands/lane)
                float dot0 = __fmaf_rn(qz, c0.z, __fmaf_rn(qy, c0.y, __fmul_rn(qx, c0.x)));
                float dist0 = __fadd_rn(__fmaf_rn(-2.f, dot0, qxx), c0.w);
                float dot1 = __fmaf_rn(qz, c1.z, __fmaf_rn(qy, c1.y, __fmul_rn(qx, c1.x)));
                float dist1 = __fadd_rn(__fmaf_rn(-2.f, dot1, qxx), c1.w);
                bool pr0 = (dist0 <= t0) && in0;
                bool pr1 = (dist1 <= t0) && in1;
                unsigned long long m0 = __ballot(pr0);
                unsigned long long m1 = __ballot(pr1);
                if (m0 | m1) {
                    unsigned n0c = (unsigned)__popcll(m0);
                    unsigned pos0 = cnt + (unsigned)__popcll(m0 & lt);
                    unsigned pos1 = cnt + n0c + (unsigned)__popcll(m1 & lt);
                    if (pr0 && pos0 < CAPQ) {
                        int corig = SO[jc0];
                        int db = __float_as_int(dist0);
                        unsigned key = (unsigned)db ^ (unsigned)((db >> 31) | 0x80000000);
                        pb[pos0] = ((unsigned long long)key << 32) | (unsigned)corig;
                    }
                    if (pr1 && pos1 < CAPQ) {
                        int corig = SO[jc1];
                        int db = __float_as_int(dist1);
                        unsigned key = (unsigned)db ^ (unsigned)((db >> 31) | 0x80000000);
                        pb[pos1] = ((unsigned long long)key << 32) | (unsigned)corig;
                    }
                    cnt += n0c + (unsigned)__popcll(m1);
                }
                yb = yb2; p = p2; hi = hi2; have = have2;
                jc0 = jn0; jc1 = jn1; c0 = n0; c1 = n1; in0 = inn0; in1 = inn1;
            }
            if (cnt < KN) {
                tlo = t0;
                t0 = (thi > 0.f) ? __fsqrt_rn(tlo * thi) : t0 * 2.0f;
            } else if (cnt > CAPQ) {
                thi = t0;
                t0 = (tlo > 0.f) ? __fsqrt_rn(tlo * thi) : t0 * 0.5f;
            } else break;                        // accepted: stack = all passers
        }

        // ---- selection: counting-rank over the stack (CAPQ=64 -> 1/lane) ----
        unsigned tot = cnt > CAPQ ? CAPQ : cnt;
        unsigned long long e0 = ((unsigned)lane < tot) ? pb[lane] : ~0ull;
        unsigned rank0 = 0;
        for (unsigned jx = 0; jx < tot; ++jx) {
            unsigned long long v = pb[jx];      // uniform addr -> LDS broadcast
            rank0 += (v < e0) ? 1u : 0u;
        }
        if (((unsigned)lane < tot) && rank0 < KN)
            g_idx[(b * NN + qorig) * KN + rank0] = (int)(e0 & 0xffffffffull);
    }
}

// ---------------- kernel 4: gather+max, rel, out = Wh' * rel ----------------
__global__ __launch_bounds__(256) void k_out(const float* __restrict__ Wh,
        float* __restrict__ out) {
    __shared__ float whs[CC * FE];
    int tid = threadIdx.x;
    for (int i = tid; i < CC * FE; i += 256) {
        int c = i >> 5, e = i & 31;
        float s = 0.f;
        #pragma unroll
        for (int m = 0; m < 4; ++m) s += Wh[c * 128 + m * 32 + e];
        whs[i] = s;
    }
    __syncthreads();
    int b = blockIdx.x >> 5;
    int n = ((blockIdx.x & 31) << 8) + tid;
    const int* ip = g_idx + (size_t)(b * NN + n) * KN;
    const float4* f0 = (const float4*)(g_feat0 + (size_t)b * NN * FE);
    float gmax[FE];
    #pragma unroll
    for (int e = 0; e < FE; ++e) gmax[e] = -__builtin_inff();
    for (int k = 0; k < KN; ++k) {
        int id = ip[k] & (NN - 1);      // defensive mask, no-op for valid idx
        const float4* row = f0 + (size_t)id * 8;
        #pragma unroll
        for (int e0 = 0; e0 < 8; ++e0) {
            float4 v = row[e0];
            gmax[e0 * 4 + 0] = fmaxf(gmax[e0 * 4 + 0], v.x);
            gmax[e0 * 4 + 1] = fmaxf(gmax[e0 * 4 + 1], v.y);
            gmax[e0 * 4 + 2] = fmaxf(gmax[e0 * 4 + 2], v.z);
            gmax[e0 * 4 + 3] = fmaxf(gmax[e0 * 4 + 3], v.w);
        }
    }
    const float4* selfr = f0 + (size_t)n * 8;
    float rel[FE];
    #pragma unroll
    for (int e0 = 0; e0 < 8; ++e0) {
        float4 v = selfr[e0];
        rel[e0 * 4 + 0] = gmax[e0 * 4 + 0] - v.x;
        rel[e0 * 4 + 1] = gmax[e0 * 4 + 1] - v.y;
        rel[e0 * 4 + 2] = gmax[e0 * 4 + 2] - v.z;
        rel[e0 * 4 + 3] = gmax[e0 * 4 + 3] - v.w;
    }
    float* op = out + (size_t)b * CC * NN + n;
    for (int c = 0; c < CC; ++c) {
        const float4* w4 = (const float4*)(whs + c * FE);
        float s = 0.f;
        #pragma unroll
        for (int e0 = 0; e0 < 8; ++e0) {
            float4 w = w4[e0];
            s = fmaf(w.x, rel[e0 * 4 + 0], s);
            s = fmaf(w.y, rel[e0 * 4 + 1], s);
            s = fmaf(w.z, rel[e0 * 4 + 2], s);
            s = fmaf(w.w, rel[e0 * 4 + 3], s);
        }
        op[(size_t)c * NN] = s;
    }
}

extern "C" void kernel_launch(void* const* d_in, const int* in_sizes, int n_in,
                              void* d_out, int out_size, void* d_ws, size_t ws_size,
                              hipStream_t stream) {
    const float* xyz   = (const float*)d_in[0];
    const float* feat  = (const float*)d_in[1];
    const float* gamma = (const float*)d_in[2];
    const float* beta  = (const float*)d_in[3];
    const float* Wg    = (const float*)d_in[4];
    const float* Wh    = (const float*)d_in[5];
    float* out = (float*)d_out;
    (void)d_ws; (void)ws_size;

    hipLaunchKernelGGL(k_bnstats, dim3(512),  dim3(256),  0, stream, feat);
    hipLaunchKernelGGL(k_zbin,    dim3(8),    dim3(1024), 0, stream, xyz);
    hipLaunchKernelGGL(k_feat0,   dim3(256),  dim3(256),  0, stream, feat, xyz, Wg, gamma, beta);
    hipLaunchKernelGGL(k_knn,     dim3(4096), dim3(256),  0, stream);
    hipLaunchKernelGGL(k_out,     dim3(256),  dim3(256),  0, stream, Wh, out);
}